// Round 2
// baseline (763.452 us; speedup 1.0000x reference)
//
#include <hip/hip_runtime.h>
#include <hip/hip_bf16.h>

#define N 512
#define HID 1024
#define OUTN 131328            // N + N*(N-1)/2
#define J4 (OUTN / 4)          // 32832 float4 columns
#define KCH 8                  // K-split chunks for the big GEMV
#define KCHUNK (HID / KCH)     // 128

typedef float v4f __attribute__((ext_vector_type(4)));

// y[j] = tanh(b[j] + sum_k x[k] * W[k*HID + j]); W row-major (DIN, HID).
// Block: 256 threads = 16 outputs x 16 k-groups. Grid: HID/16 = 64.
// DIN templated so the K loop fully unrolls -> all loads in flight at once.
template <int DIN>
__global__ __launch_bounds__(256) void gemv_tanh_kernel(
    const float* __restrict__ x, const float* __restrict__ W,
    const float* __restrict__ b, float* __restrict__ y) {
  constexpr int CH = DIN / 16;
  __shared__ float xs[DIN];
  __shared__ float red[16][17];
  int tx = threadIdx.x;
  for (int i = tx; i < DIN; i += 256) xs[i] = x[i];
  __syncthreads();
  int jl = tx & 15;
  int kg = tx >> 4;
  int j = blockIdx.x * 16 + jl;
  int k0 = kg * CH;
  float acc = 0.f;
#pragma unroll
  for (int i = 0; i < CH; ++i) {
    int k = k0 + i;
    acc += xs[k] * W[(size_t)k * HID + j];
  }
  red[kg][jl] = acc;
  __syncthreads();
  if (tx < 16) {
    float s = 0.f;
#pragma unroll
    for (int g = 0; g < 16; ++g) s += red[g][tx];
    int jj = blockIdx.x * 16 + tx;
    y[jj] = tanhf(s + b[jj]);
  }
}

// Partial big GEMV: P[chunk][j] = sum_{k in chunk} h[k] * Wo[k*OUTN + j]
// One float4 (4 outputs) per thread; blockIdx.y selects the K chunk.
// Wo is streamed once -> nontemporal loads (don't pollute L2).
__global__ __launch_bounds__(256) void big_gemv_partial(
    const float* __restrict__ h, const float* __restrict__ Wo,
    float* __restrict__ P) {
  __shared__ float hs[KCHUNK];
  int tx = threadIdx.x;
  int k0 = blockIdx.y * KCHUNK;
  if (tx < KCHUNK) hs[tx] = h[k0 + tx];
  __syncthreads();
  int j4 = blockIdx.x * 256 + tx;
  if (j4 >= J4) return;
  const float* base = Wo + (size_t)k0 * OUTN + 4 * (size_t)j4;
  v4f acc = {0.f, 0.f, 0.f, 0.f};
#pragma unroll 8
  for (int kk = 0; kk < KCHUNK; ++kk) {
    v4f w = __builtin_nontemporal_load((const v4f*)(base + (size_t)kk * OUTN));
    acc += hs[kk] * w;
  }
  *(v4f*)(P + (size_t)blockIdx.y * OUTN + 4 * (size_t)j4) = acc;
}

// Build L (512x512): fuse the 8-way partial reduce + bias; exp on diag; zeros above.
__global__ __launch_bounds__(256) void build_L_kernel(
    const float* __restrict__ P, const float* __restrict__ bo,
    float* __restrict__ L) {
  int t = blockIdx.x * 256 + threadIdx.x;
  int i = t >> 9;        // row
  int c = t & 511;       // col
  float v = 0.f;
  if (c <= i) {
    int idx = (c == i) ? i : (N + i * (i - 1) / 2 + c);
    float s = bo[idx];
#pragma unroll
    for (int ch = 0; ch < KCH; ++ch) s += P[(size_t)ch * OUTN + idx];
    v = (c == i) ? expf(s) : s;
  }
  L[t] = v;
}

// D = L * L^T, tiled 32x32, skipping k-tiles beyond min(bi,bj)+31 (L lower-tri).
__global__ __launch_bounds__(256) void syrk_kernel(
    const float* __restrict__ L, float* __restrict__ D) {
  __shared__ float A[32][33];
  __shared__ float B[32][33];
  int tx = threadIdx.x;  // 0..31
  int ty = threadIdx.y;  // 0..7
  int bi = blockIdx.y * 32;
  int bj = blockIdx.x * 32;
  float acc[4] = {0.f, 0.f, 0.f, 0.f};
  int ktmax = (bi < bj ? bi : bj) + 32;
  for (int kt = 0; kt < ktmax; kt += 32) {
    for (int r = ty; r < 32; r += 8) {
      A[r][tx] = L[(size_t)(bi + r) * N + kt + tx];
      B[r][tx] = L[(size_t)(bj + r) * N + kt + tx];
    }
    __syncthreads();
#pragma unroll
    for (int k = 0; k < 32; ++k) {
      float bv = B[tx][k];
#pragma unroll
      for (int m = 0; m < 4; ++m) acc[m] += A[ty + 8 * m][k] * bv;
    }
    __syncthreads();
  }
#pragma unroll
  for (int m = 0; m < 4; ++m)
    D[(size_t)(bi + ty + 8 * m) * N + bj + tx] = acc[m];
}

extern "C" void kernel_launch(void* const* d_in, const int* in_sizes, int n_in,
                              void* d_out, int out_size, void* d_ws, size_t ws_size,
                              hipStream_t stream) {
  const float* input = (const float*)d_in[0];
  const float* W0 = (const float*)d_in[1];
  const float* b0 = (const float*)d_in[2];
  const float* W1 = (const float*)d_in[3];
  const float* b1 = (const float*)d_in[4];
  const float* W2 = (const float*)d_in[5];
  const float* b2 = (const float*)d_in[6];
  const float* Wo = (const float*)d_in[7];
  const float* bo = (const float*)d_in[8];

  float* ws = (float*)d_ws;
  float* h0 = ws;                       // 1024
  float* h1 = ws + 1024;                // 1024
  float* h2 = ws + 2048;                // 1024
  float* P  = ws + 4096;                // KCH * OUTN = 1,050,624
  float* L  = ws + 4096 + KCH * OUTN;   // 262,144
  float* D  = (float*)d_out;

  gemv_tanh_kernel<512><<<HID / 16, 256, 0, stream>>>(input, W0, b0, h0);
  gemv_tanh_kernel<HID><<<HID / 16, 256, 0, stream>>>(h0, W1, b1, h1);
  gemv_tanh_kernel<HID><<<HID / 16, 256, 0, stream>>>(h1, W2, b2, h2);

  dim3 gB((J4 + 255) / 256, KCH);
  big_gemv_partial<<<gB, 256, 0, stream>>>(h2, Wo, P);

  build_L_kernel<<<(N * N) / 256, 256, 0, stream>>>(P, bo, L);

  dim3 gS(N / 32, N / 32);
  syrk_kernel<<<gS, dim3(32, 8), 0, stream>>>(L, D);
}

// Round 3
// 735.947 us; speedup vs baseline: 1.0374x; 1.0374x over previous
//
#include <hip/hip_runtime.h>
#include <hip/hip_bf16.h>

#define N 512
#define HID 1024
#define OUTN 131328            // N + N*(N-1)/2
#define J4 (OUTN / 4)          // 32832 float4 columns
#define KCH 16                 // K-split chunks for the big GEMV
#define KCHUNK (HID / KCH)     // 64

typedef float v4f __attribute__((ext_vector_type(4)));

// y[j..j+3] = tanh(b + sum_k x[k] * W[k][j..j+3]); W row-major (DIN, HID).
// Block: 256 threads = 16 j4-groups x 16 k-groups. Grid: HID/64 = 16.
// Fully unrolled K loop -> all float4 loads in flight.
template <int DIN>
__global__ __launch_bounds__(256) void gemv_tanh_kernel(
    const float* __restrict__ x, const float* __restrict__ W,
    const float* __restrict__ b, float* __restrict__ y) {
  constexpr int CH = DIN / 16;
  __shared__ float xs[DIN];
  __shared__ v4f red[16][16];
  int tx = threadIdx.x;
  for (int i = tx; i < DIN; i += 256) xs[i] = x[i];
  __syncthreads();
  int jl = tx & 15;            // j4 within block
  int kg = tx >> 4;            // k-group
  int j = (blockIdx.x * 16 + jl) * 4;
  int k0 = kg * CH;
  v4f acc = {0.f, 0.f, 0.f, 0.f};
#pragma unroll
  for (int i = 0; i < CH; ++i) {
    int k = k0 + i;
    v4f w = *(const v4f*)(W + (size_t)k * HID + j);
    acc += xs[k] * w;
  }
  red[kg][jl] = acc;
  __syncthreads();
  if (tx < 16) {
    v4f s = {0.f, 0.f, 0.f, 0.f};
#pragma unroll
    for (int g = 0; g < 16; ++g) s += red[g][tx];
    int jj = (blockIdx.x * 16 + tx) * 4;
    v4f bb = *(const v4f*)(b + jj);
    s += bb;
    float4 o;
    o.x = tanhf(s.x); o.y = tanhf(s.y); o.z = tanhf(s.z); o.w = tanhf(s.w);
    *(float4*)(y + jj) = o;
  }
}

// Partial big GEMV: P[chunk][j] = sum_{k in chunk} h[k] * Wo[k*OUTN + j]
// One float4 (4 outputs) per thread; blockIdx.y selects the K chunk.
// KCH=16 -> 2064 blocks -> 8 blocks/CU -> 32 waves/CU (full occupancy).
// Wo is streamed once -> nontemporal loads (don't pollute L2).
__global__ __launch_bounds__(256) void big_gemv_partial(
    const float* __restrict__ h, const float* __restrict__ Wo,
    float* __restrict__ P) {
  __shared__ float hs[KCHUNK];
  int tx = threadIdx.x;
  int k0 = blockIdx.y * KCHUNK;
  if (tx < KCHUNK) hs[tx] = h[k0 + tx];
  __syncthreads();
  int j4 = blockIdx.x * 256 + tx;
  if (j4 >= J4) return;
  const float* base = Wo + (size_t)k0 * OUTN + 4 * (size_t)j4;
  v4f acc = {0.f, 0.f, 0.f, 0.f};
#pragma unroll 8
  for (int kk = 0; kk < KCHUNK; ++kk) {
    v4f w = __builtin_nontemporal_load((const v4f*)(base + (size_t)kk * OUTN));
    acc += hs[kk] * w;
  }
  *(v4f*)(P + (size_t)blockIdx.y * OUTN + 4 * (size_t)j4) = acc;
}

// Build L (512x512): fuse the 16-way partial reduce + bias; exp on diag; zeros above.
__global__ __launch_bounds__(256) void build_L_kernel(
    const float* __restrict__ P, const float* __restrict__ bo,
    float* __restrict__ L) {
  int t = blockIdx.x * 256 + threadIdx.x;
  int i = t >> 9;        // row
  int c = t & 511;       // col
  float v = 0.f;
  if (c <= i) {
    int idx = (c == i) ? i : (N + i * (i - 1) / 2 + c);
    float s = bo[idx];
#pragma unroll
    for (int ch = 0; ch < KCH; ++ch) s += P[(size_t)ch * OUTN + idx];
    v = (c == i) ? expf(s) : s;
  }
  L[t] = v;
}

// D = L * L^T, tiled 32x32, skipping k-tiles beyond min(bi,bj)+31 (L lower-tri).
__global__ __launch_bounds__(256) void syrk_kernel(
    const float* __restrict__ L, float* __restrict__ D) {
  __shared__ float A[32][33];
  __shared__ float B[32][33];
  int tx = threadIdx.x;  // 0..31
  int ty = threadIdx.y;  // 0..7
  int bi = blockIdx.y * 32;
  int bj = blockIdx.x * 32;
  float acc[4] = {0.f, 0.f, 0.f, 0.f};
  int ktmax = (bi < bj ? bi : bj) + 32;
  for (int kt = 0; kt < ktmax; kt += 32) {
    for (int r = ty; r < 32; r += 8) {
      A[r][tx] = L[(size_t)(bi + r) * N + kt + tx];
      B[r][tx] = L[(size_t)(bj + r) * N + kt + tx];
    }
    __syncthreads();
#pragma unroll
    for (int k = 0; k < 32; ++k) {
      float bv = B[tx][k];
#pragma unroll
      for (int m = 0; m < 4; ++m) acc[m] += A[ty + 8 * m][k] * bv;
    }
    __syncthreads();
  }
#pragma unroll
  for (int m = 0; m < 4; ++m)
    D[(size_t)(bi + ty + 8 * m) * N + bj + tx] = acc[m];
}

extern "C" void kernel_launch(void* const* d_in, const int* in_sizes, int n_in,
                              void* d_out, int out_size, void* d_ws, size_t ws_size,
                              hipStream_t stream) {
  const float* input = (const float*)d_in[0];
  const float* W0 = (const float*)d_in[1];
  const float* b0 = (const float*)d_in[2];
  const float* W1 = (const float*)d_in[3];
  const float* b1 = (const float*)d_in[4];
  const float* W2 = (const float*)d_in[5];
  const float* b2 = (const float*)d_in[6];
  const float* Wo = (const float*)d_in[7];
  const float* bo = (const float*)d_in[8];

  float* ws = (float*)d_ws;
  float* h0 = ws;                       // 1024
  float* h1 = ws + 1024;                // 1024
  float* h2 = ws + 2048;                // 1024
  float* P  = ws + 4096;                // KCH * OUTN
  float* L  = ws + 4096 + KCH * OUTN;   // 262,144
  float* D  = (float*)d_out;

  gemv_tanh_kernel<512><<<HID / 64, 256, 0, stream>>>(input, W0, b0, h0);
  gemv_tanh_kernel<HID><<<HID / 64, 256, 0, stream>>>(h0, W1, b1, h1);
  gemv_tanh_kernel<HID><<<HID / 64, 256, 0, stream>>>(h1, W2, b2, h2);

  dim3 gB((J4 + 255) / 256, KCH);
  big_gemv_partial<<<gB, 256, 0, stream>>>(h2, Wo, P);

  build_L_kernel<<<(N * N) / 256, 256, 0, stream>>>(P, bo, L);

  dim3 gS(N / 32, N / 32);
  syrk_kernel<<<gS, dim3(32, 8), 0, stream>>>(L, D);
}